// Round 10
// baseline (104.396 us; speedup 1.0000x reference)
//
#include <hip/hip_runtime.h>
#include <hip/hip_bf16.h>

// Problem constants: B=2, H=1, LQ=LK=512, D=64, HID=128
// rows (B*H*L) = 1024 for q/k/v each.

#define NROWS 1024   // B*H*LQ
#define DD    64
#define HH    128
#define LK_   512
#define QR    4      // query rows per attn block

// ---------------------------------------------------------------------------
// Kernel A: projections + transposed k-table emit + Wd-folded v-projection.
// (unchanged from round 9)
// ---------------------------------------------------------------------------
__global__ __launch_bounds__(128)
void proj_kernel(const float* __restrict__ q, const float* __restrict__ k,
                 const float* __restrict__ v,
                 const float* __restrict__ Ww, const float* __restrict__ wb,
                 const float* __restrict__ W1, const float* __restrict__ b1,
                 const float* __restrict__ Wd,
                 float* __restrict__ vpd,
                 float* __restrict__ qa, float* __restrict__ qb,
                 float* __restrict__ kaTf, float* __restrict__ kbTf)
{
    const int r    = blockIdx.x;
    const int type = r >> 10;      // 0=q,1=k,2=v
    const int idx  = r & 1023;
    const int t    = threadIdx.x;  // 0..127

    const float* src = (type == 0) ? q : (type == 1) ? k : v;

    __shared__ float x[DD];
    __shared__ float xp[DD];

    if (t < DD) x[t] = src[idx * DD + t];
    __syncthreads();

    if (t < DD) {
        float acc = wb[t];
        #pragma unroll
        for (int c = 0; c < DD; ++c) acc = fmaf(x[c], Ww[c * DD + t], acc);
        xp[t] = acc;
    }
    __syncthreads();

    if (type == 2) {
        // vpd = xp @ Wd   (threads 0..63)
        if (t < DD) {
            float acc = 0.f;
            #pragma unroll
            for (int c = 0; c < DD; ++c) acc = fmaf(xp[c], Wd[c * DD + t], acc);
            vpd[idx * DD + t] = acc;
        }
        return;
    }

    // thread t = output column h of the HID=128 projections
    float accA = 0.f;   // xp @ W1q  (W1 rows 0..63)
    float accB = 0.f;   // xp @ W1k  (W1 rows 64..127)
    #pragma unroll
    for (int d = 0; d < DD; ++d) {
        const float xv = xp[d];
        accA = fmaf(xv, W1[d * HH + t],        accA);
        accB = fmaf(xv, W1[(DD + d) * HH + t], accB);
    }
    if (type == 0) {
        qa[idx * HH + t] = accA + b1[t];
        qb[idx * HH + t] = accB + b1[t];
    } else {
        // transposed emit: h-chunked float4 layout [b][h4][j][c]
        const int b  = idx >> 9;
        const int j  = idx & (LK_ - 1);
        const int o  = ((b * (HH / 4) + (t >> 2)) * LK_ + j) * 4 + (t & 3);
        kaTf[o] = accA;
        kbTf[o] = accB;
    }
}

// ---------------------------------------------------------------------------
// Kernel B: fused logits + softmax + PV + bias.
// grid = 256 blocks (QR=4 q-rows), block = 512 threads (8 waves).
// (2,2) thread tile: rp = t>>8 (wave-uniform row-pair), thread covers
//   rows {row0+2rp, row0+2rp+1} x cols {t&255, (t&255)+256}.
// Per h4-iter: 4 scalar dwordx4 (q-side, SMEM — HALVED vs (4,1))
//            + 4 vector dwordx4 (k-side, coalesced; cross-rp dupes hit L1)
//            + 1 W2 dwordx4 + 96 VALU.
// ---------------------------------------------------------------------------
__global__ __launch_bounds__(512)
void attn_kernel(const float* __restrict__ mask,
                 const float* __restrict__ vpd,
                 const float* __restrict__ qa, const float* __restrict__ qb,
                 const float4* __restrict__ kaT, const float4* __restrict__ kbT,
                 const float* __restrict__ W2, const float* __restrict__ b2,
                 const float* __restrict__ db,
                 float* __restrict__ out, float* __restrict__ attn)
{
    const int row0 = blockIdx.x * QR;   // first of 4 query rows (4 | 512)
    const int b    = row0 >> 9;
    const int t    = threadIdx.x;       // 0..511
    const int wid  = t >> 6;            // wave 0..7
    const int lane = t & 63;
    const int rp   = t >> 8;            // 0/1 row-pair selector (wave-uniform)
    const int j1   = t & 255;
    const int j2   = j1 + 256;

    __shared__ float p_int[LK_ * QR];   // [j][rlocal] -> b128 broadcast in PV
    __shared__ float redm[8][2];
    __shared__ float reds[8][2];
    __shared__ float opart[8][QR][DD];

    const float4* kaTb = kaT + b * (HH / 4) * LK_;
    const float4* kbTb = kbT + b * (HH / 4) * LK_;
    const float*  qaR  = qa + (row0 + 2 * rp) * HH;   // wave-uniform -> s_load
    const float*  qbR  = qb + (row0 + 2 * rp) * HH;
    const float4* w24  = reinterpret_cast<const float4*>(W2);

    // prefetch mask early (overlaps hot loop)
    float mk[2][2];
    #pragma unroll
    for (int r = 0; r < 2; ++r) {
        mk[r][0] = mask[(row0 + 2 * rp + r) * LK_ + j1];
        mk[r][1] = mask[(row0 + 2 * rp + r) * LK_ + j2];
    }

    // ---- logits: 2 rows x 2 cols x (2 relu-dot terms over HID=128) ----
    float s1[2][2] = {{0.f, 0.f}, {0.f, 0.f}};
    float s2[2][2] = {{0.f, 0.f}, {0.f, 0.f}};
    #pragma unroll 2
    for (int h4 = 0; h4 < HH / 4; ++h4) {
        const float4 w    = w24[h4];
        const float4 kb4a = kbTb[h4 * LK_ + j1];
        const float4 ka4a = kaTb[h4 * LK_ + j1];
        const float4 kb4b = kbTb[h4 * LK_ + j2];
        const float4 ka4b = kaTb[h4 * LK_ + j2];
        const int h = h4 * 4;
        #pragma unroll
        for (int r = 0; r < 2; ++r) {
            const float qa0 = qaR[r * HH + h + 0], qa1 = qaR[r * HH + h + 1];
            const float qa2 = qaR[r * HH + h + 2], qa3 = qaR[r * HH + h + 3];
            const float qb0 = qbR[r * HH + h + 0], qb1 = qbR[r * HH + h + 1];
            const float qb2 = qbR[r * HH + h + 2], qb3 = qbR[r * HH + h + 3];
            s1[r][0] = fmaf(fmaxf(qa0 + kb4a.x, 0.f), w.x, s1[r][0]);
            s1[r][0] = fmaf(fmaxf(qa1 + kb4a.y, 0.f), w.y, s1[r][0]);
            s1[r][0] = fmaf(fmaxf(qa2 + kb4a.z, 0.f), w.z, s1[r][0]);
            s1[r][0] = fmaf(fmaxf(qa3 + kb4a.w, 0.f), w.w, s1[r][0]);
            s1[r][1] = fmaf(fmaxf(qa0 + kb4b.x, 0.f), w.x, s1[r][1]);
            s1[r][1] = fmaf(fmaxf(qa1 + kb4b.y, 0.f), w.y, s1[r][1]);
            s1[r][1] = fmaf(fmaxf(qa2 + kb4b.z, 0.f), w.z, s1[r][1]);
            s1[r][1] = fmaf(fmaxf(qa3 + kb4b.w, 0.f), w.w, s1[r][1]);
            s2[r][0] = fmaf(fmaxf(qb0 + ka4a.x, 0.f), w.x, s2[r][0]);
            s2[r][0] = fmaf(fmaxf(qb1 + ka4a.y, 0.f), w.y, s2[r][0]);
            s2[r][0] = fmaf(fmaxf(qb2 + ka4a.z, 0.f), w.z, s2[r][0]);
            s2[r][0] = fmaf(fmaxf(qb3 + ka4a.w, 0.f), w.w, s2[r][0]);
            s2[r][1] = fmaf(fmaxf(qb0 + ka4b.x, 0.f), w.x, s2[r][1]);
            s2[r][1] = fmaf(fmaxf(qb1 + ka4b.y, 0.f), w.y, s2[r][1]);
            s2[r][1] = fmaf(fmaxf(qb2 + ka4b.z, 0.f), w.z, s2[r][1]);
            s2[r][1] = fmaf(fmaxf(qb3 + ka4b.w, 0.f), w.w, s2[r][1]);
        }
    }

    const float b2v = b2[0];
    float sv[2][2];
    #pragma unroll
    for (int r = 0; r < 2; ++r) {
        sv[r][0] = s1[r][0] + s2[r][0] + 2.f * b2v + mk[r][0] * (-1e9f);
        sv[r][1] = s1[r][1] + s2[r][1] + 2.f * b2v + mk[r][1] * (-1e9f);
    }

    // ---- softmax: row (row0+2rp+r) lives in waves 4rp..4rp+3, 2 j each ----
    float m[2];
    #pragma unroll
    for (int r = 0; r < 2; ++r) {
        float mv = fmaxf(sv[r][0], sv[r][1]);
        #pragma unroll
        for (int off = 32; off > 0; off >>= 1) mv = fmaxf(mv, __shfl_xor(mv, off));
        if (lane == 0) redm[wid][r] = mv;
    }
    __syncthreads();
    #pragma unroll
    for (int r = 0; r < 2; ++r) {
        const int g = 4 * rp;
        m[r] = fmaxf(fmaxf(redm[g][r], redm[g + 1][r]),
                     fmaxf(redm[g + 2][r], redm[g + 3][r]));
    }

    float e[2][2];
    #pragma unroll
    for (int r = 0; r < 2; ++r) {
        e[r][0] = expf(sv[r][0] - m[r]);
        e[r][1] = expf(sv[r][1] - m[r]);
        float s = e[r][0] + e[r][1];
        #pragma unroll
        for (int off = 32; off > 0; off >>= 1) s += __shfl_xor(s, off);
        if (lane == 0) reds[wid][r] = s;
    }
    __syncthreads();

    float pv[2][2];
    #pragma unroll
    for (int r = 0; r < 2; ++r) {
        const int g = 4 * rp;
        const float s = reds[g][r] + reds[g + 1][r] + reds[g + 2][r] + reds[g + 3][r];
        const float inv = 1.f / s;
        pv[r][0] = e[r][0] * inv;
        pv[r][1] = e[r][1] * inv;
        attn[(row0 + 2 * rp + r) * LK_ + j1] = pv[r][0];
        attn[(row0 + 2 * rp + r) * LK_ + j2] = pv[r][1];
    }
    // p_int[j][rlocal]; thread writes rlocal {2rp, 2rp+1} for j1 and j2
    *reinterpret_cast<float2*>(&p_int[j1 * QR + 2 * rp]) =
        make_float2(pv[0][0], pv[1][0]);
    *reinterpret_cast<float2*>(&p_int[j2 * QR + 2 * rp]) =
        make_float2(pv[0][1], pv[1][1]);
    __syncthreads();

    // ---- PV: wave wid handles j in [wid*64, wid*64+64), lane = d ----
    float acc[QR] = {0.f, 0.f, 0.f, 0.f};
    {
        const int jb = wid * 64;
        const float* vb = vpd + (b * LK_ + jb) * DD;
        #pragma unroll 8
        for (int jj = 0; jj < 64; ++jj) {
            const float4 pj = *reinterpret_cast<const float4*>(&p_int[(jb + jj) * QR]);
            const float vv = vb[jj * DD + lane];
            acc[0] = fmaf(pj.x, vv, acc[0]);
            acc[1] = fmaf(pj.y, vv, acc[1]);
            acc[2] = fmaf(pj.z, vv, acc[2]);
            acc[3] = fmaf(pj.w, vv, acc[3]);
        }
    }
    #pragma unroll
    for (int r = 0; r < QR; ++r) opart[wid][r][lane] = acc[r];
    __syncthreads();

    // ---- combine 8 wave partials + bias -> out ----
    if (t < QR * DD) {
        const int r = t >> 6, d = t & 63;
        float o = opart[0][r][d];
        #pragma unroll
        for (int w = 1; w < 8; ++w) o += opart[w][r][d];
        out[(row0 + r) * DD + d] = o + db[d];
    }
}

extern "C" void kernel_launch(void* const* d_in, const int* in_sizes, int n_in,
                              void* d_out, int out_size, void* d_ws, size_t ws_size,
                              hipStream_t stream)
{
    const float* q    = (const float*)d_in[0];
    const float* k    = (const float*)d_in[1];
    const float* v    = (const float*)d_in[2];
    const float* mask = (const float*)d_in[3];
    const float* Ww   = (const float*)d_in[4];
    const float* wb   = (const float*)d_in[5];
    const float* Wd   = (const float*)d_in[6];
    const float* db   = (const float*)d_in[7];
    const float* W1   = (const float*)d_in[8];
    const float* b1   = (const float*)d_in[9];
    const float* W2   = (const float*)d_in[10];
    const float* b2   = (const float*)d_in[11];

    float* ws = (float*)d_ws;
    float* vpd = ws;                    // 1024*64   (= (v@Ww+wb)@Wd)
    float* qa  = vpd + NROWS * DD;      // 1024*128
    float* qb  = qa + NROWS * HH;
    float* kaTf = qb + NROWS * HH;      // 2*32*512*4 floats = 512 KB
    float* kbTf = kaTf + NROWS * HH;
    // total ws use ≈ 2.3 MB

    float* out  = (float*)d_out;        // 2*1*512*64
    float* attn = out + NROWS * DD;     // 2*1*512*512

    proj_kernel<<<dim3(3072), dim3(128), 0, stream>>>(
        q, k, v, Ww, wb, W1, b1, Wd, vpd, qa, qb, kaTf, kbTf);

    attn_kernel<<<dim3(NROWS / QR), dim3(512), 0, stream>>>(
        mask, vpd, qa, qb, (const float4*)kaTf, (const float4*)kbTf,
        W2, b2, db, out, attn);
}